// Round 2
// baseline (115.569 us; speedup 1.0000x reference)
//
#include <hip/hip_runtime.h>

#define N_SAMPLES 4096
#define DIM 2048
#define NUM_CLASSES 128
#define MARGIN 0.5f

// ---------------- ws layout (byte offsets) ----------------
// cnt   : C ints        @ 0
// meanR : C*D floats    @ 1024
// meanT : C*D floats    @ 1024 + C*D*4
//
// History:
//   R3  = 118.8 us (4-deep unroll mean, 256-block loss).
//   R5  (nontemporal + 8-deep unroll): +13 us — regression.
//   R6  (loss algebraic refactor): +7 us — reverted.
//   R8  = 115.4 us: loss 4-waves/tile (kept); mean 8-deep pipeline WITH
//         register copies (v=w) — copies force s_waitcnt vmcnt(0) per
//         group, so latency stayed exposed. Partial win only.
//   R9  (this): mean = copy-free ping-pong (load B / acc A / load A /
//         acc B -> waits become vmcnt(8), 8 loads always in flight) and
//         the <=7-row tail as ONE clamp-masked group whose loads issue
//         FIRST (hidden under the body). Loss unchanged.

// Kernel 1: per-class means, self-contained (no pre-sort).
// grid (2, C, 2), block 256. Each block scans targets (16 KB, L2-hot),
// compacts its class's rows into LDS, then streams its rows' float4
// columns with a copy-free ping-pong pipeline. Inputs read exactly once.
__global__ __launch_bounds__(256) void mean_kernel(
        const float* __restrict__ x1,
        const float* __restrict__ x2,
        const int* __restrict__ targets,
        int* __restrict__ cnt,
        float* __restrict__ meanR,
        float* __restrict__ meanT,
        float* __restrict__ d_out, int out_size) {
    __shared__ int s_rows[N_SAMPLES];
    __shared__ int s_n;
    const int tid = threadIdx.x;
    const int c = blockIdx.y;
    const float* __restrict__ x = (blockIdx.z == 0) ? x1 : x2;
    float* __restrict__ mean    = (blockIdx.z == 0) ? meanR : meanT;

    if (tid == 0) s_n = 0;
    if (blockIdx.x == 0 && blockIdx.y == 0 && blockIdx.z == 0) {
        for (int i = tid; i < out_size; i += 256) d_out[i] = 0.0f;  // loss runs after us
    }
    __syncthreads();

    // compact rows of class c (order irrelevant)
    const int4* __restrict__ t4 = (const int4*)targets;
    for (int i = tid; i < N_SAMPLES / 4; i += 256) {
        const int4 v = t4[i];
        const int base = i * 4;
        if (v.x == c) s_rows[atomicAdd(&s_n, 1)] = base;
        if (v.y == c) s_rows[atomicAdd(&s_n, 1)] = base + 1;
        if (v.z == c) s_rows[atomicAdd(&s_n, 1)] = base + 2;
        if (v.w == c) s_rows[atomicAdd(&s_n, 1)] = base + 3;
    }
    __syncthreads();
    const int n = s_n;

    const int col = blockIdx.x * 256 + tid;          // float4 index in [0,512)
    const float4* __restrict__ xs = (const float4*)x;
    float ax = 0.0f, ay = 0.0f, az = 0.0f, aw = 0.0f;

#define LOADG(B, g) do {                                               \
        const int _base = (g) * 8;                                     \
        _Pragma("unroll")                                              \
        for (int u = 0; u < 8; ++u) {                                  \
            const int _r = s_rows[_base + u];                          \
            B[u] = xs[(size_t)_r * (DIM / 4) + col];                   \
        }                                                              \
    } while (0)

#define ACCG(B) do {                                                   \
        _Pragma("unroll")                                              \
        for (int u = 0; u < 8; ++u) {                                  \
            ax += B[u].x; ay += B[u].y; az += B[u].z; aw += B[u].w;    \
        }                                                              \
    } while (0)

    const int nfull = n >> 3;        // full 8-row groups
    const int rem   = n & 7;         // 0..7 tail rows

    // Tail group: clamped indices, loads issued FIRST so their latency
    // hides under the whole body; masked accumulate at the very end.
    float4 T[8];
    if (rem) {
        const int tbase = nfull * 8;
#pragma unroll
        for (int u = 0; u < 8; ++u) {
            const int idx = tbase + ((u < rem) ? u : 0);  // clamp (uniform)
            T[u] = xs[(size_t)s_rows[idx] * (DIM / 4) + col];
        }
    }

    // Copy-free ping-pong body: acc(X) waits vmcnt(8) while the other
    // group's 8 loads remain in flight. No register moves, no drains.
    if (nfull > 0) {
        float4 bufA[8], bufB[8];
        LOADG(bufA, 0);
        int g = 1;
        for (; g + 1 < nfull; g += 2) {
            LOADG(bufB, g);
            ACCG(bufA);
            LOADG(bufA, g + 1);
            ACCG(bufB);
        }
        if (g < nfull) {             // one loaded group + one pending
            LOADG(bufB, g);
            ACCG(bufA);
            ACCG(bufB);
        } else {
            ACCG(bufA);
        }
    }

    if (rem) {
#pragma unroll
        for (int u = 0; u < 8; ++u) {
            const float m = (u < rem) ? 1.0f : 0.0f;
            ax = fmaf(T[u].x, m, ax);
            ay = fmaf(T[u].y, m, ay);
            az = fmaf(T[u].z, m, az);
            aw = fmaf(T[u].w, m, aw);
        }
    }
#undef LOADG
#undef ACCG

    const float inv = 1.0f / (float)((n > 0) ? n : 1);
    float4 m; m.x = ax * inv; m.y = ay * inv; m.z = az * inv; m.w = aw * inv;
    ((float4*)mean)[(size_t)c * (DIM / 4) + col] = m;

    if (blockIdx.x == 0 && blockIdx.z == 0 && tid == 0) cnt[c] = n;
}

__device__ __forceinline__ void accum_sq(float& acc, const float4& a, const float4& c) {
    float d;
    d = a.x - c.x; acc = fmaf(d, d, acc);
    d = a.y - c.y; acc = fmaf(d, d, acc);
    d = a.z - c.z; acc = fmaf(d, d, acc);
    d = a.w - c.w; acc = fmaf(d, d, acc);
}

__device__ __forceinline__ float wave_sum64(float v) {
#pragma unroll
    for (int m = 32; m >= 1; m >>= 1) v += __shfl_xor(v, m, 64);
    return v;
}

// Kernel 2: class-pair distances + contrastive terms.
// One BLOCK per 4a x 4b tile (1024 blocks); the block's 4 waves each cover
// a quarter of D. Partial squared distances combined in LDS BEFORE the
// sqrt/relu nonlinearity. 4096 waves (4/SIMD). Means (2 MB) L2-resident.
__global__ __launch_bounds__(256) void loss_kernel(
        const float* __restrict__ meanR,
        const float* __restrict__ meanT,
        const int* __restrict__ cnt,
        float* __restrict__ d_out) {
    const int tile = blockIdx.x;         // 0..1023
    const int a0 = (tile >> 5) * 4;      // a-tile: 4 classes
    const int b0 = (tile & 31) * 4;      // b-tile: 4 classes
    const int wave = threadIdx.x >> 6;   // 0..3 -> quarter of D
    const int lane = threadIdx.x & 63;

    float acc1[4][4], acc2[4][4];
#pragma unroll
    for (int i = 0; i < 4; ++i)
#pragma unroll
        for (int j = 0; j < 4; ++j) { acc1[i][j] = 0.0f; acc2[i][j] = 0.0f; }

#pragma unroll
    for (int it = 0; it < 2; ++it) {
        const int d = wave * 128 + it * 64 + lane;   // float4 index within a row
        float4 ra[4], ta[4];
#pragma unroll
        for (int i = 0; i < 4; ++i) {
            ra[i] = ((const float4*)(meanR + (size_t)(a0 + i) * DIM))[d];
            ta[i] = ((const float4*)(meanT + (size_t)(a0 + i) * DIM))[d];
        }
#pragma unroll
        for (int j = 0; j < 4; ++j) {
            const int b = b0 + j;
            const float4 rb = ((const float4*)(meanR + (size_t)b * DIM))[d];
            const float4 tb = ((const float4*)(meanT + (size_t)b * DIM))[d];
            float4 cb;
            cb.x = 0.5f * (rb.x + tb.x);
            cb.y = 0.5f * (rb.y + tb.y);
            cb.z = 0.5f * (rb.z + tb.z);
            cb.w = 0.5f * (rb.w + tb.w);
#pragma unroll
            for (int i = 0; i < 4; ++i) {
                accum_sq(acc1[i][j], ra[i], cb);
                accum_sq(acc2[i][j], ta[i], cb);
            }
        }
    }

#pragma unroll
    for (int i = 0; i < 4; ++i)
#pragma unroll
        for (int j = 0; j < 4; ++j) {
            acc1[i][j] = wave_sum64(acc1[i][j]);
            acc2[i][j] = wave_sum64(acc2[i][j]);
        }

    // combine the 4 per-wave D-partials before the nonlinearity
    __shared__ float s1[4][16], s2[4][16];
    if (lane == 0) {
#pragma unroll
        for (int i = 0; i < 4; ++i)
#pragma unroll
            for (int j = 0; j < 4; ++j) {
                s1[wave][i * 4 + j] = acc1[i][j];
                s2[wave][i * 4 + j] = acc2[i][j];
            }
    }
    __syncthreads();

    if (threadIdx.x < 64) {
        float total = 0.0f;
        if (threadIdx.x < 16) {
            const int idx = threadIdx.x;
            const int i = idx >> 2, j = idx & 3;
            const int a = a0 + i, b = b0 + j;
            const float sqa1 = (s1[0][idx] + s1[1][idx]) + (s1[2][idx] + s1[3][idx]);
            const float sqa2 = (s2[0][idx] + s2[1][idx]) + (s2[2][idx] + s2[3][idx]);
            const float invN2 = 1.0f / ((float)N_SAMPLES * (float)N_SAMPLES);
            const float w = (float)cnt[a] * (float)cnt[b] * invN2;
            const float sq1 = fmaxf(sqa1, 1e-12f);
            const float sq2 = fmaxf(sqa2, 1e-12f);
            float t1, t2;
            if (a == b) {
                t1 = sq1;                 // label==1: d2^2 == clamped sq
                t2 = sq2;
            } else {
                const float dd1 = sqrtf(sqrtf(sq1) + 1e-10f);
                const float dd2 = sqrtf(sqrtf(sq2) + 1e-10f);
                const float r1 = fmaxf(MARGIN - dd1, 0.0f);
                const float r2 = fmaxf(MARGIN - dd2, 0.0f);
                t1 = r1 * r1;
                t2 = r2 * r2;
            }
            total = w * (t1 + t2);
        }
        total = wave_sum64(total);       // lanes 16..63 contribute 0
        if (threadIdx.x == 0) atomicAdd(d_out, total);
    }
}

extern "C" void kernel_launch(void* const* d_in, const int* in_sizes, int n_in,
                              void* d_out, int out_size, void* d_ws, size_t ws_size,
                              hipStream_t stream) {
    const float* modal1 = (const float*)d_in[0];
    const float* modal2 = (const float*)d_in[1];
    const int* targets  = (const int*)d_in[2];
    float* out = (float*)d_out;

    char* ws = (char*)d_ws;
    int*   cnt   = (int*)(ws + 0);
    float* meanR = (float*)(ws + 1024);
    float* meanT = (float*)(ws + 1024 + (size_t)NUM_CLASSES * DIM * 4);

    // 1. per-class means (self-gathering; also zeroes d_out, publishes cnt)
    dim3 gridB(2, NUM_CLASSES, 2);
    mean_kernel<<<gridB, 256, 0, stream>>>(modal1, modal2, targets, cnt,
                                           meanR, meanT, out, out_size);

    // 2. class-pair losses -> scalar (one 4x4 tile per block, 4 waves split D)
    loss_kernel<<<NUM_CLASSES / 4 * NUM_CLASSES / 4, 256, 0, stream>>>(
        meanR, meanT, cnt, out);
}